// Round 7
// baseline (299.380 us; speedup 1.0000x reference)
//
#include <hip/hip_runtime.h>
#include <hip/hip_bf16.h>

#define NB 16
#define NW 64
#define NV 64
#define ND 256
#define NR 64
#define NN 4096
#define NEGV -10000000000.0f

typedef __attribute__((ext_vector_type(8))) short short8;
typedef __attribute__((ext_vector_type(4))) float f32x4;

__device__ inline float cvt(const void* p, int idx, int flag) {
  if (flag) return __bfloat162float(((const __hip_bfloat16*)p)[idx]);
  return ((const float*)p)[idx];
}
__device__ inline void stv(void* p, int idx, float v, int flag) {
  if (flag) ((__hip_bfloat16*)p)[idx] = __float2bfloat16(v);
  else ((float*)p)[idx] = v;
}
__device__ inline float bf2f(short s) {
  return __uint_as_float(((unsigned int)(unsigned short)s) << 16);
}
__device__ inline float tanh_fast(float x) {
  float ax = fabsf(x);
  float e = __expf(-2.f * ax);
  float r = (1.f - e) / (1.f + e);
  return copysignf(r, x);
}

// ---------- K0: detect input dtype (bf16 vs f32) ----------
__global__ void k_detect(const unsigned int* embw, int* flagp) {
  __shared__ float red[256];
  int t = threadIdx.x;
  float mx = 0.f;
  for (int i = t; i < 1024; i += 256) {
    unsigned int w = embw[i];
    unsigned int fb = (w & 0xffffu) << 16;
    float a = fabsf(__uint_as_float(fb));
    if (!(a < 1e9f)) a = 1e9f;
    mx = fmaxf(mx, a);
  }
  red[t] = mx;
  __syncthreads();
  for (int s = 128; s > 0; s >>= 1) {
    if (t < s) red[t] = fmaxf(red[t], red[t + s]);
    __syncthreads();
  }
  if (t == 0) flagp[0] = (red[0] < 1000.f) ? 1 : 0;
}

// ---------- K1 (merged prep): relaT | small params | w1 pack | gather ----------
__global__ void k_prep(const void* rela, float* relaT,
                       const void* b1, const void* w2, const void* outw,
                       const void* b2, const void* outb, float* sp,
                       const void* w1, __hip_bfloat16* w1b,
                       const int* head, const int* tail, const void* emb,
                       float* Af, float* Bf, const int* flagp) {
  int flag = flagp[0];
  int blk = blockIdx.x;
  int t = threadIdx.x;
  if (blk < 64) {
    relaT[t * NR + blk] = cvt(rela, blk * ND + t, flag);
  } else if (blk == 64) {
    sp[t] = cvt(b1, t, flag);
    sp[256 + t] = cvt(w2, t, flag);
    sp[512 + t] = cvt(outw, t, flag);
    if (t == 0) {
      sp[768] = cvt(b2, 0, flag);
      sp[769] = cvt(outb, 0, flag);
    }
  } else if (blk < 321) {
    int flat = (blk - 65) * 256 + t;  // 65536
    int i = flat & 7;
    int lane = (flat >> 3) & 63;
    int kst = (flat >> 9) & 7;
    int nt = flat >> 12;
    int k = kst * 32 + (lane >> 4) * 8 + i;
    int n = nt * 16 + (lane & 15);
    w1b[flat] = __float2bfloat16(cvt(w1, k * ND + n, flag));
  } else {
    int row = blk - 321;  // 0..2047
    if (row < NB * NW) {
      int ix = head[row];
      Af[row * ND + t] = cvt(emb, ix * ND + t, flag);
    } else {
      int rr = row - NB * NW;
      int ix = tail[rr];
      Bf[rr * ND + t] = cvt(emb, ix * ND + t, flag);
    }
  }
}

// ---------- K3: Ah = A@Wa + fc_b, Bh = B@Wb, RWb = pack(rela@Wc) ----------
__global__ void __launch_bounds__(256) k_premm(const float* __restrict__ Af,
                                               const float* __restrict__ Bf,
                                               const void* __restrict__ rela,
                                               const void* __restrict__ fcw,
                                               const void* __restrict__ fcb,
                                               float* __restrict__ Ah,
                                               float* __restrict__ Bh,
                                               __hip_bfloat16* __restrict__ rwb,
                                               const int* __restrict__ flagp) {
  int flag = flagp[0];
  int blk = blockIdx.x;
  int t = threadIdx.x;
  __shared__ float rl[4][ND];
  int base, wbase, addb = 0, isr = 0;
  const float* src = Af;
  if (blk < 256) { base = blk * 4; wbase = 0; addb = 1; }
  else if (blk < 512) { base = (blk - 256) * 4; src = Bf; wbase = ND; }
  else { base = (blk - 512) * 4; wbase = 2 * ND; isr = 1; }
#pragma unroll
  for (int i = 0; i < 4; ++i)
    rl[i][t] = isr ? cvt(rela, (base + i) * ND + t, flag)
                   : src[(base + i) * ND + t];
  __syncthreads();
  float acc0 = 0.f, acc1 = 0.f, acc2 = 0.f, acc3 = 0.f;
  const f32x4* r0p = (const f32x4*)rl[0];
  const f32x4* r1p = (const f32x4*)rl[1];
  const f32x4* r2p = (const f32x4*)rl[2];
  const f32x4* r3p = (const f32x4*)rl[3];
#pragma unroll 4
  for (int k4 = 0; k4 < 64; ++k4) {
    float w0 = cvt(fcw, (wbase + k4 * 4 + 0) * ND + t, flag);
    float w1v = cvt(fcw, (wbase + k4 * 4 + 1) * ND + t, flag);
    float w2v = cvt(fcw, (wbase + k4 * 4 + 2) * ND + t, flag);
    float w3v = cvt(fcw, (wbase + k4 * 4 + 3) * ND + t, flag);
    f32x4 r0 = r0p[k4], r1 = r1p[k4], r2 = r2p[k4], r3 = r3p[k4];
    acc0 += r0.x * w0 + r0.y * w1v + r0.z * w2v + r0.w * w3v;
    acc1 += r1.x * w0 + r1.y * w1v + r1.z * w2v + r1.w * w3v;
    acc2 += r2.x * w0 + r2.y * w1v + r2.z * w2v + r2.w * w3v;
    acc3 += r3.x * w0 + r3.y * w1v + r3.z * w2v + r3.w * w3v;
  }
  float bias = addb ? cvt(fcb, t, flag) : 0.f;
  float res[4] = {acc0 + bias, acc1 + bias, acc2 + bias, acc3 + bias};
  if (!isr) {
    float* dst = addb ? Ah : Bh;
#pragma unroll
    for (int i = 0; i < 4; ++i) dst[(base + i) * ND + t] = res[i];
  } else {
#pragma unroll
    for (int i = 0; i < 4; ++i) {
      int rr = base + i;
      int ks = rr >> 5, ii = rr & 7, lh = (rr >> 3) & 3;
      int nt = t >> 4, ll = t & 15;
      int flat = ((nt * 2 + ks) * 64 + lh * 16 + ll) * 8 + ii;
      rwb[flat] = __float2bfloat16(res[i]);
    }
  }
}

// ---------- K4: scores -> mask -> softmax -> norm_scores ----------
// B operands read as WAVE-UNIFORM scalar loads (q is wave-uniform) — no LDS
// staging, no staging barrier. Per-(b,i,j) FP op order is bit-identical to
// R4/R5 (knife-edge s<=null mask must stay bit-stable f32).
__global__ void __launch_bounds__(256) k_scores(const float* __restrict__ Af,
                                                const float* __restrict__ Bf,
                                                const float* __restrict__ relaT,
                                                void* __restrict__ out,
                                                __hip_bfloat16* __restrict__ nsb,
                                                const int* __restrict__ flagp) {
  int flag = flagp[0];
  int bi = blockIdx.x;         // 1024 = b*64 + i
  int b = bi >> 6;
  int t = threadIdx.x;         // 256
  int r = t & 63;
  int q = __builtin_amdgcn_readfirstlane(t >> 6);  // wave-uniform d-quarter
  __shared__ float Al[ND];
  __shared__ float part[4 * 256];
  Al[t] = Af[bi * ND + t];
  __syncthreads();
  float preR[64];
#pragma unroll
  for (int i2 = 0; i2 < 64; ++i2) {
    int d = q * 64 + i2;
    preR[i2] = Al[d] * relaT[d * NR + r];
  }
  const float* __restrict__ Bbase = Bf + (size_t)b * NV * ND + q * 64;
  for (int jg = 0; jg < 16; ++jg) {
#pragma unroll
    for (int jj = 0; jj < 4; ++jj) {
      const float* __restrict__ Bj = Bbase + (size_t)(jg * 4 + jj) * ND;
      float acc = 0.f;
#pragma unroll
      for (int i4 = 0; i4 < 16; ++i4) {
        acc += preR[i4 * 4 + 0] * Bj[i4 * 4 + 0];
        acc += preR[i4 * 4 + 1] * Bj[i4 * 4 + 1];
        acc += preR[i4 * 4 + 2] * Bj[i4 * 4 + 2];
        acc += preR[i4 * 4 + 3] * Bj[i4 * 4 + 3];
      }
      part[jj * 256 + t] = acc;
    }
    __syncthreads();
    {
      int j4 = q;   // this wave's j within the group
      float s = part[j4 * 256 + r] + part[j4 * 256 + 64 + r]
              + part[j4 * 256 + 128 + r] + part[j4 * 256 + 192 + r];
      float nullv = __shfl(s, 63, 64);
      float m = (s <= nullv) ? NEGV : s;
      float mx = m;
#pragma unroll
      for (int o = 32; o > 0; o >>= 1) mx = fmaxf(mx, __shfl_xor(mx, o, 64));
      float e = __expf(m - mx);
      float sum = e;
#pragma unroll
      for (int o = 32; o > 0; o >>= 1) sum += __shfl_xor(sum, o, 64);
      float ns = e / sum;
      int j = jg * 4 + j4;
      int nidx = (bi * 64 + j) * 64 + r;
      stv(out, 16 + NB * NN + nidx, ns, flag);
      nsb[nidx] = __float2bfloat16(ns);
    }
    __syncthreads();
  }
}

// ---------- K5 (fused MFMA): tuple = tanh(NS@RW + Ah + Bh) kept in LDS;
//            att_raw = tanh(T@W1+b1)@w2+b2 ; dotv = T@out_w ----------
// Block = one bi (64 rows). Stage 1: K=64 MFMA -> tanh -> bf16 LDS tile
// (stride 264 shorts, <=2-way bank aliasing). Stage 2: A-frags from LDS,
// T@W1 MFMA + dotv + epilogue. tup never touches HBM.
__global__ void __launch_bounds__(256) k_tupatt(
    const __hip_bfloat16* __restrict__ nsb, const __hip_bfloat16* __restrict__ rwb,
    const float* __restrict__ Ah, const float* __restrict__ Bh,
    const __hip_bfloat16* __restrict__ w1b, const float* __restrict__ sp,
    float* __restrict__ att_raw, float* __restrict__ dotv) {
  __shared__ __align__(16) short tl[64 * 264];
  int t = threadIdx.x;
  int wv = t >> 6, lane = t & 63;
  int bi = blockIdx.x;       // 1024
  int b = bi >> 6;
  const short* nsS = (const short*)nsb;
  const short* rwS = (const short*)rwb;
  const short* w1S = (const short*)w1b;
  int m = lane & 15;
  int kgrp = lane >> 4;

  // ---- stage 1: NS@RW (M=16/wave, N=256, K=64) ----
  f32x4 acc[16];
#pragma unroll
  for (int i = 0; i < 16; ++i) acc[i] = (f32x4){0.f, 0.f, 0.f, 0.f};
  int nrow = bi * 64 + wv * 16 + m;
#pragma unroll
  for (int ks = 0; ks < 2; ++ks) {
    short8 a = *(const short8*)(nsS + (size_t)nrow * 64 + ks * 32 + kgrp * 8);
#pragma unroll
    for (int nt = 0; nt < 16; ++nt) {
      short8 bfr = *(const short8*)(rwS + (((nt * 2 + ks) * 64 + lane) << 3));
      acc[nt] = __builtin_amdgcn_mfma_f32_16x16x32_bf16(a, bfr, acc[nt], 0, 0, 0);
    }
  }
  // C layout: local row = wv*16 + kgrp*4 + reg, col = nt*16 + m
  int rl0 = wv * 16 + kgrp * 4;
#pragma unroll
  for (int nt = 0; nt < 16; ++nt) {
    int col = nt * 16 + m;
    float ahv = Ah[bi * ND + col];
#pragma unroll
    for (int reg = 0; reg < 4; ++reg) {
      float v = acc[nt][reg] + ahv + Bh[(size_t)(b * 64 + rl0 + reg) * ND + col];
      __hip_bfloat16 hb = __float2bfloat16(tanh_fast(v));
      tl[(rl0 + reg) * 264 + col] = *(short*)&hb;
    }
  }
  __syncthreads();

  // ---- stage 2: T@W1 + dotv + epilogue (rows wv*16..wv*16+15) ----
  const float* owf = sp + 512;
  float b2v = sp[768];
  f32x4 acc2[16];
#pragma unroll
  for (int i = 0; i < 16; ++i) acc2[i] = (f32x4){0.f, 0.f, 0.f, 0.f};
  float dp = 0.f;
  int arow = wv * 16 + m;
#pragma unroll
  for (int ks = 0; ks < 8; ++ks) {
    int k0 = ks * 32 + kgrp * 8;
    short8 a = *(const short8*)(tl + arow * 264 + k0);
#pragma unroll
    for (int i = 0; i < 8; ++i) dp += bf2f(a[i]) * owf[k0 + i];
#pragma unroll
    for (int nt = 0; nt < 16; ++nt) {
      short8 bfr = *(const short8*)(w1S + (((nt * 8 + ks) * 64 + lane) << 3));
      acc2[nt] = __builtin_amdgcn_mfma_f32_16x16x32_bf16(a, bfr, acc2[nt], 0, 0, 0);
    }
  }
  dp += __shfl_xor(dp, 16, 64);
  dp += __shfl_xor(dp, 32, 64);
  if (lane < 16) dotv[bi * 64 + wv * 16 + lane] = dp;

  float p0[4] = {0.f, 0.f, 0.f, 0.f};
#pragma unroll
  for (int nt = 0; nt < 16; ++nt) {
    int col = nt * 16 + m;
    float b1v = sp[col];
    float w2v = sp[256 + col];
#pragma unroll
    for (int reg = 0; reg < 4; ++reg)
      p0[reg] += tanh_fast(acc2[nt][reg] + b1v) * w2v;
  }
#pragma unroll
  for (int o = 1; o < 16; o <<= 1) {
#pragma unroll
    for (int reg = 0; reg < 4; ++reg)
      p0[reg] += __shfl_xor(p0[reg], o, 64);
  }
  if (m == 0) {
    int rb = bi * 64 + wv * 16 + kgrp * 4;
#pragma unroll
    for (int reg = 0; reg < 4; ++reg)
      att_raw[rb + reg] = p0[reg] + b2v;
  }
}

// ---------- K7: att softmax over N -> att_norms out; logits ----------
__global__ void k_fuse(const float* att_raw, const float* dotv,
                       const float* sp, void* out, const int* flagp) {
  int flag = flagp[0];
  int b = blockIdx.x;
  int t = threadIdx.x;
  __shared__ float red[256];
  float vals[16];
  float mx = -3.4e38f;
#pragma unroll
  for (int c = 0; c < 16; ++c) {
    vals[c] = att_raw[b * NN + c * 256 + t];
    mx = fmaxf(mx, vals[c]);
  }
  red[t] = mx;
  __syncthreads();
  for (int s = 128; s > 0; s >>= 1) {
    if (t < s) red[t] = fmaxf(red[t], red[t + s]);
    __syncthreads();
  }
  float M = red[0];
  __syncthreads();
  float sm = 0.f;
#pragma unroll
  for (int c = 0; c < 16; ++c) {
    vals[c] = __expf(vals[c] - M);
    sm += vals[c];
  }
  red[t] = sm;
  __syncthreads();
  for (int s = 128; s > 0; s >>= 1) {
    if (t < s) red[t] += red[t + s];
    __syncthreads();
  }
  float Z = red[0];
  __syncthreads();
  float acc = 0.f;
#pragma unroll
  for (int c = 0; c < 16; ++c) {
    int n = c * 256 + t;
    float a = vals[c] / Z;
    stv(out, 16 + b * NN + n, a, flag);
    acc += a * dotv[b * NN + n];
  }
  red[t] = acc;
  __syncthreads();
  for (int s = 128; s > 0; s >>= 1) {
    if (t < s) red[t] += red[t + s];
    __syncthreads();
  }
  if (t == 0) stv(out, b, red[0] + sp[769], flag);   // + out_b
}

// ---------- host ----------
extern "C" void kernel_launch(void* const* d_in, const int* in_sizes, int n_in,
                              void* d_out, int out_size, void* d_ws, size_t ws_size,
                              hipStream_t stream) {
  const int* head = (const int*)d_in[0];
  const int* tail = (const int*)d_in[1];
  const void* emb = d_in[2];
  const void* rela = d_in[3];
  const void* fcw = d_in[4];
  const void* fcb = d_in[5];
  const void* w1 = d_in[6];
  const void* b1 = d_in[7];
  const void* w2 = d_in[8];
  const void* b2 = d_in[9];
  const void* outw = d_in[10];
  const void* outb = d_in[11];

  float* ws = (float*)d_ws;
  int* flagp = (int*)d_ws;
  const size_t O_RELAT = 16;
  const size_t O_AF = O_RELAT + 16384;
  const size_t O_BF = O_AF + 262144;
  const size_t O_AH = O_BF + 262144;
  const size_t O_BH = O_AH + 262144;
  const size_t O_ATTR = O_BH + 262144;
  const size_t O_DOT = O_ATTR + 65536;
  const size_t O_SP = O_DOT + 65536;
  const size_t O_W1B = O_SP + 1024;        // 65536 bf16
  const size_t O_RWB = O_W1B + 32768;      // 16384 bf16
  const size_t O_NSB = O_RWB + 8192;       // 4.19M bf16

  float* relaT = ws + O_RELAT;
  float* Af = ws + O_AF;
  float* Bf = ws + O_BF;
  float* Ah = ws + O_AH;
  float* Bh = ws + O_BH;
  float* attr = ws + O_ATTR;
  float* dotv = ws + O_DOT;
  float* sp = ws + O_SP;
  __hip_bfloat16* w1b = (__hip_bfloat16*)(ws + O_W1B);
  __hip_bfloat16* rwb = (__hip_bfloat16*)(ws + O_RWB);
  __hip_bfloat16* nsb = (__hip_bfloat16*)(ws + O_NSB);

  hipLaunchKernelGGL(k_detect, dim3(1), dim3(256), 0, stream,
                     (const unsigned int*)emb, flagp);
  hipLaunchKernelGGL(k_prep, dim3(2369), dim3(256), 0, stream,
                     rela, relaT, b1, w2, outw, b2, outb, sp,
                     w1, w1b, head, tail, emb, Af, Bf, flagp);
  hipLaunchKernelGGL(k_premm, dim3(528), dim3(256), 0, stream,
                     Af, Bf, rela, fcw, fcb, Ah, Bh, rwb, flagp);
  hipLaunchKernelGGL(k_scores, dim3(1024), dim3(256), 0, stream,
                     Af, Bf, relaT, d_out, nsb, flagp);
  hipLaunchKernelGGL(k_tupatt, dim3(1024), dim3(256), 0, stream,
                     nsb, rwb, Ah, Bh, w1b, sp, attr, dotv);
  hipLaunchKernelGGL(k_fuse, dim3(16), dim3(256), 0, stream,
                     attr, dotv, sp, d_out, flagp);
}

// Round 8
// 262.542 us; speedup vs baseline: 1.1403x; 1.1403x over previous
//
#include <hip/hip_runtime.h>
#include <hip/hip_bf16.h>

#define NB 16
#define NW 64
#define NV 64
#define ND 256
#define NR 64
#define NN 4096
#define NEGV -10000000000.0f

typedef __attribute__((ext_vector_type(8))) short short8;
typedef __attribute__((ext_vector_type(4))) float f32x4;

__device__ inline float cvt(const void* p, int idx, int flag) {
  if (flag) return __bfloat162float(((const __hip_bfloat16*)p)[idx]);
  return ((const float*)p)[idx];
}
__device__ inline void stv(void* p, int idx, float v, int flag) {
  if (flag) ((__hip_bfloat16*)p)[idx] = __float2bfloat16(v);
  else ((float*)p)[idx] = v;
}
__device__ inline float bf2f(short s) {
  return __uint_as_float(((unsigned int)(unsigned short)s) << 16);
}
__device__ inline float tanh_fast(float x) {
  float ax = fabsf(x);
  float e = __expf(-2.f * ax);
  float r = (1.f - e) / (1.f + e);
  return copysignf(r, x);
}

// ---------- K0: detect input dtype (bf16 vs f32) ----------
__global__ void k_detect(const unsigned int* embw, int* flagp) {
  __shared__ float red[256];
  int t = threadIdx.x;
  float mx = 0.f;
  for (int i = t; i < 1024; i += 256) {
    unsigned int w = embw[i];
    unsigned int fb = (w & 0xffffu) << 16;
    float a = fabsf(__uint_as_float(fb));
    if (!(a < 1e9f)) a = 1e9f;
    mx = fmaxf(mx, a);
  }
  red[t] = mx;
  __syncthreads();
  for (int s = 128; s > 0; s >>= 1) {
    if (t < s) red[t] = fmaxf(red[t], red[t + s]);
    __syncthreads();
  }
  if (t == 0) flagp[0] = (red[0] < 1000.f) ? 1 : 0;
}

// ---------- K1 (merged prep): relaT | small params | w1 pack | gather ----------
__global__ void k_prep(const void* rela, float* relaT,
                       const void* b1, const void* w2, const void* outw,
                       const void* b2, const void* outb, float* sp,
                       const void* w1, __hip_bfloat16* w1b,
                       const int* head, const int* tail, const void* emb,
                       float* Af, float* Bf, const int* flagp) {
  int flag = flagp[0];
  int blk = blockIdx.x;
  int t = threadIdx.x;
  if (blk < 64) {
    relaT[t * NR + blk] = cvt(rela, blk * ND + t, flag);
  } else if (blk == 64) {
    sp[t] = cvt(b1, t, flag);
    sp[256 + t] = cvt(w2, t, flag);
    sp[512 + t] = cvt(outw, t, flag);
    if (t == 0) {
      sp[768] = cvt(b2, 0, flag);
      sp[769] = cvt(outb, 0, flag);
    }
  } else if (blk < 321) {
    int flat = (blk - 65) * 256 + t;  // 65536
    int i = flat & 7;
    int lane = (flat >> 3) & 63;
    int kst = (flat >> 9) & 7;
    int nt = flat >> 12;
    int k = kst * 32 + (lane >> 4) * 8 + i;
    int n = nt * 16 + (lane & 15);
    w1b[flat] = __float2bfloat16(cvt(w1, k * ND + n, flag));
  } else {
    int row = blk - 321;  // 0..2047
    if (row < NB * NW) {
      int ix = head[row];
      Af[row * ND + t] = cvt(emb, ix * ND + t, flag);
    } else {
      int rr = row - NB * NW;
      int ix = tail[rr];
      Bf[rr * ND + t] = cvt(emb, ix * ND + t, flag);
    }
  }
}

// ---------- K3: Ah = A@Wa + fc_b, Bh = B@Wb, RWb = pack(rela@Wc) ----------
__global__ void __launch_bounds__(256) k_premm(const float* __restrict__ Af,
                                               const float* __restrict__ Bf,
                                               const void* __restrict__ rela,
                                               const void* __restrict__ fcw,
                                               const void* __restrict__ fcb,
                                               float* __restrict__ Ah,
                                               float* __restrict__ Bh,
                                               __hip_bfloat16* __restrict__ rwb,
                                               const int* __restrict__ flagp) {
  int flag = flagp[0];
  int blk = blockIdx.x;
  int t = threadIdx.x;
  __shared__ float rl[4][ND];
  int base, wbase, addb = 0, isr = 0;
  const float* src = Af;
  if (blk < 256) { base = blk * 4; wbase = 0; addb = 1; }
  else if (blk < 512) { base = (blk - 256) * 4; src = Bf; wbase = ND; }
  else { base = (blk - 512) * 4; wbase = 2 * ND; isr = 1; }
#pragma unroll
  for (int i = 0; i < 4; ++i)
    rl[i][t] = isr ? cvt(rela, (base + i) * ND + t, flag)
                   : src[(base + i) * ND + t];
  __syncthreads();
  float acc0 = 0.f, acc1 = 0.f, acc2 = 0.f, acc3 = 0.f;
  const f32x4* r0p = (const f32x4*)rl[0];
  const f32x4* r1p = (const f32x4*)rl[1];
  const f32x4* r2p = (const f32x4*)rl[2];
  const f32x4* r3p = (const f32x4*)rl[3];
#pragma unroll 4
  for (int k4 = 0; k4 < 64; ++k4) {
    float w0 = cvt(fcw, (wbase + k4 * 4 + 0) * ND + t, flag);
    float w1v = cvt(fcw, (wbase + k4 * 4 + 1) * ND + t, flag);
    float w2v = cvt(fcw, (wbase + k4 * 4 + 2) * ND + t, flag);
    float w3v = cvt(fcw, (wbase + k4 * 4 + 3) * ND + t, flag);
    f32x4 r0 = r0p[k4], r1 = r1p[k4], r2 = r2p[k4], r3 = r3p[k4];
    acc0 += r0.x * w0 + r0.y * w1v + r0.z * w2v + r0.w * w3v;
    acc1 += r1.x * w0 + r1.y * w1v + r1.z * w2v + r1.w * w3v;
    acc2 += r2.x * w0 + r2.y * w1v + r2.z * w2v + r2.w * w3v;
    acc3 += r3.x * w0 + r3.y * w1v + r3.z * w2v + r3.w * w3v;
  }
  float bias = addb ? cvt(fcb, t, flag) : 0.f;
  float res[4] = {acc0 + bias, acc1 + bias, acc2 + bias, acc3 + bias};
  if (!isr) {
    float* dst = addb ? Ah : Bh;
#pragma unroll
    for (int i = 0; i < 4; ++i) dst[(base + i) * ND + t] = res[i];
  } else {
#pragma unroll
    for (int i = 0; i < 4; ++i) {
      int rr = base + i;
      int ks = rr >> 5, ii = rr & 7, lh = (rr >> 3) & 3;
      int nt = t >> 4, ll = t & 15;
      int flat = ((nt * 2 + ks) * 64 + lh * 16 + ll) * 8 + ii;
      rwb[flat] = __float2bfloat16(res[i]);
    }
  }
}

// ---------- K4: scores -> mask -> softmax -> norm_scores ----------
// B operands read as WAVE-UNIFORM scalar loads (q is wave-uniform).
// part[] double-buffered -> ONE barrier per jg. Per-(b,i,j) FP op order is
// bit-identical to R4..R7 (knife-edge s<=null mask must stay bit-stable f32).
__global__ void __launch_bounds__(256) k_scores(const float* __restrict__ Af,
                                                const float* __restrict__ Bf,
                                                const float* __restrict__ relaT,
                                                void* __restrict__ out,
                                                __hip_bfloat16* __restrict__ nsb,
                                                const int* __restrict__ flagp) {
  int flag = flagp[0];
  int bi = blockIdx.x;         // 1024 = b*64 + i
  int b = bi >> 6;
  int t = threadIdx.x;         // 256
  int r = t & 63;
  int q = __builtin_amdgcn_readfirstlane(t >> 6);  // wave-uniform d-quarter
  __shared__ float Al[ND];
  __shared__ float part[2][4 * 256];
  Al[t] = Af[bi * ND + t];
  __syncthreads();
  float preR[64];
#pragma unroll
  for (int i2 = 0; i2 < 64; ++i2) {
    int d = q * 64 + i2;
    preR[i2] = Al[d] * relaT[d * NR + r];
  }
  const float* __restrict__ Bbase = Bf + (size_t)b * NV * ND + q * 64;
  for (int jg = 0; jg < 16; ++jg) {
    float* pb = part[jg & 1];
#pragma unroll
    for (int jj = 0; jj < 4; ++jj) {
      const float* __restrict__ Bj = Bbase + (size_t)(jg * 4 + jj) * ND;
      float acc = 0.f;
#pragma unroll
      for (int i4 = 0; i4 < 16; ++i4) {
        acc += preR[i4 * 4 + 0] * Bj[i4 * 4 + 0];
        acc += preR[i4 * 4 + 1] * Bj[i4 * 4 + 1];
        acc += preR[i4 * 4 + 2] * Bj[i4 * 4 + 2];
        acc += preR[i4 * 4 + 3] * Bj[i4 * 4 + 3];
      }
      pb[jj * 256 + t] = acc;
    }
    __syncthreads();
    {
      int j4 = q;   // this wave's j within the group
      float s = pb[j4 * 256 + r] + pb[j4 * 256 + 64 + r]
              + pb[j4 * 256 + 128 + r] + pb[j4 * 256 + 192 + r];
      float nullv = __shfl(s, 63, 64);
      float m = (s <= nullv) ? NEGV : s;
      float mx = m;
#pragma unroll
      for (int o = 32; o > 0; o >>= 1) mx = fmaxf(mx, __shfl_xor(mx, o, 64));
      float e = __expf(m - mx);
      float sum = e;
#pragma unroll
      for (int o = 32; o > 0; o >>= 1) sum += __shfl_xor(sum, o, 64);
      float ns = e / sum;
      int j = jg * 4 + j4;
      int nidx = (bi * 64 + j) * 64 + r;
      stv(out, 16 + NB * NN + nidx, ns, flag);
      nsb[nidx] = __float2bfloat16(ns);
    }
  }
}

// ---------- K5 (MFMA): tuple = tanh(NS@RW + Ah + Bh) -> bf16 ----------
__global__ void __launch_bounds__(256) k_tuple2(const __hip_bfloat16* __restrict__ nsb,
                                                const __hip_bfloat16* __restrict__ rwb,
                                                const float* __restrict__ Ah,
                                                const float* __restrict__ Bh,
                                                __hip_bfloat16* __restrict__ tup) {
  int t = threadIdx.x;
  int wv = t >> 6, lane = t & 63;
  int bi = blockIdx.x;       // 1024
  int b = bi >> 6;
  const short* nsS = (const short*)nsb;
  const short* rwS = (const short*)rwb;
  int m = lane & 15;
  int kgrp = lane >> 4;
  f32x4 acc[16];
#pragma unroll
  for (int i = 0; i < 16; ++i) acc[i] = (f32x4){0.f, 0.f, 0.f, 0.f};
  int nrow = bi * 64 + wv * 16 + m;
#pragma unroll
  for (int ks = 0; ks < 2; ++ks) {
    short8 a = *(const short8*)(nsS + (size_t)nrow * 64 + ks * 32 + kgrp * 8);
#pragma unroll
    for (int nt = 0; nt < 16; ++nt) {
      short8 bfr = *(const short8*)(rwS + (((nt * 2 + ks) * 64 + lane) << 3));
      acc[nt] = __builtin_amdgcn_mfma_f32_16x16x32_bf16(a, bfr, acc[nt], 0, 0, 0);
    }
  }
  int rbase = bi * 64 + wv * 16 + (lane >> 4) * 4;
  int jbase = rbase & 63;
#pragma unroll
  for (int nt = 0; nt < 16; ++nt) {
    int col = nt * 16 + m;
    float ahv = Ah[bi * ND + col];
#pragma unroll
    for (int reg = 0; reg < 4; ++reg) {
      int ng = rbase + reg;
      float v = acc[nt][reg] + ahv + Bh[(size_t)(b * 64 + jbase + reg) * ND + col];
      tup[(size_t)ng * ND + col] = __float2bfloat16(tanh_fast(v));
    }
  }
}

// ---------- K6 (MFMA): att_raw = tanh(T@W1+b1)@w2+b2 ; dotv = T@out_w ----------
__global__ void __launch_bounds__(256) k_att2(const __hip_bfloat16* __restrict__ tup,
                                              const __hip_bfloat16* __restrict__ w1b,
                                              const float* __restrict__ sp,
                                              float* __restrict__ att_raw,
                                              float* __restrict__ dotv) {
  int t = threadIdx.x;
  int wv = t >> 6, lane = t & 63;
  int r0 = blockIdx.x * 128 + wv * 32;
  const short* tupS = (const short*)tup;
  const short* w1S = (const short*)w1b;
  const float* owf = sp + 512;
  float b2v = sp[768];

  f32x4 acc0[16], acc1[16];
#pragma unroll
  for (int i = 0; i < 16; ++i) {
    acc0[i] = (f32x4){0.f, 0.f, 0.f, 0.f};
    acc1[i] = (f32x4){0.f, 0.f, 0.f, 0.f};
  }
  float dp0 = 0.f, dp1 = 0.f;
  int arow0 = r0 + (lane & 15);
  int arow1 = arow0 + 16;
  int kgrp = lane >> 4;

#pragma unroll
  for (int ks = 0; ks < 8; ++ks) {
    int k0 = ks * 32 + kgrp * 8;
    short8 a0 = *(const short8*)(tupS + (size_t)arow0 * ND + k0);
    short8 a1 = *(const short8*)(tupS + (size_t)arow1 * ND + k0);
#pragma unroll
    for (int i = 0; i < 8; ++i) {
      float w = owf[k0 + i];
      dp0 += bf2f(a0[i]) * w;
      dp1 += bf2f(a1[i]) * w;
    }
#pragma unroll
    for (int nt = 0; nt < 16; ++nt) {
      short8 bfr = *(const short8*)(w1S + (((nt * 8 + ks) * 64 + lane) << 3));
      acc0[nt] = __builtin_amdgcn_mfma_f32_16x16x32_bf16(a0, bfr, acc0[nt], 0, 0, 0);
      acc1[nt] = __builtin_amdgcn_mfma_f32_16x16x32_bf16(a1, bfr, acc1[nt], 0, 0, 0);
    }
  }

  dp0 += __shfl_xor(dp0, 16, 64); dp0 += __shfl_xor(dp0, 32, 64);
  dp1 += __shfl_xor(dp1, 16, 64); dp1 += __shfl_xor(dp1, 32, 64);
  if (lane < 16) {
    dotv[r0 + lane] = dp0;
    dotv[r0 + 16 + lane] = dp1;
  }

  float p0[4] = {0.f, 0.f, 0.f, 0.f};
  float p1[4] = {0.f, 0.f, 0.f, 0.f};
#pragma unroll
  for (int nt = 0; nt < 16; ++nt) {
    int col = nt * 16 + (lane & 15);
    float b1v = sp[col];
    float w2v = sp[256 + col];
#pragma unroll
    for (int reg = 0; reg < 4; ++reg) {
      p0[reg] += tanh_fast(acc0[nt][reg] + b1v) * w2v;
      p1[reg] += tanh_fast(acc1[nt][reg] + b1v) * w2v;
    }
  }
#pragma unroll
  for (int o = 1; o < 16; o <<= 1) {
#pragma unroll
    for (int reg = 0; reg < 4; ++reg) {
      p0[reg] += __shfl_xor(p0[reg], o, 64);
      p1[reg] += __shfl_xor(p1[reg], o, 64);
    }
  }
  if ((lane & 15) == 0) {
    int rb = r0 + (lane >> 4) * 4;
#pragma unroll
    for (int reg = 0; reg < 4; ++reg) {
      att_raw[rb + reg] = p0[reg] + b2v;
      att_raw[rb + 16 + reg] = p1[reg] + b2v;
    }
  }
}

// ---------- K7: att softmax over N -> att_norms out; logits ----------
__global__ void k_fuse(const float* att_raw, const float* dotv,
                       const float* sp, void* out, const int* flagp) {
  int flag = flagp[0];
  int b = blockIdx.x;
  int t = threadIdx.x;
  __shared__ float red[256];
  float vals[16];
  float mx = -3.4e38f;
#pragma unroll
  for (int c = 0; c < 16; ++c) {
    vals[c] = att_raw[b * NN + c * 256 + t];
    mx = fmaxf(mx, vals[c]);
  }
  red[t] = mx;
  __syncthreads();
  for (int s = 128; s > 0; s >>= 1) {
    if (t < s) red[t] = fmaxf(red[t], red[t + s]);
    __syncthreads();
  }
  float M = red[0];
  __syncthreads();
  float sm = 0.f;
#pragma unroll
  for (int c = 0; c < 16; ++c) {
    vals[c] = __expf(vals[c] - M);
    sm += vals[c];
  }
  red[t] = sm;
  __syncthreads();
  for (int s = 128; s > 0; s >>= 1) {
    if (t < s) red[t] += red[t + s];
    __syncthreads();
  }
  float Z = red[0];
  __syncthreads();
  float acc = 0.f;
#pragma unroll
  for (int c = 0; c < 16; ++c) {
    int n = c * 256 + t;
    float a = vals[c] / Z;
    stv(out, 16 + b * NN + n, a, flag);
    acc += a * dotv[b * NN + n];
  }
  red[t] = acc;
  __syncthreads();
  for (int s = 128; s > 0; s >>= 1) {
    if (t < s) red[t] += red[t + s];
    __syncthreads();
  }
  if (t == 0) stv(out, b, red[0] + sp[769], flag);   // + out_b
}

// ---------- host ----------
extern "C" void kernel_launch(void* const* d_in, const int* in_sizes, int n_in,
                              void* d_out, int out_size, void* d_ws, size_t ws_size,
                              hipStream_t stream) {
  const int* head = (const int*)d_in[0];
  const int* tail = (const int*)d_in[1];
  const void* emb = d_in[2];
  const void* rela = d_in[3];
  const void* fcw = d_in[4];
  const void* fcb = d_in[5];
  const void* w1 = d_in[6];
  const void* b1 = d_in[7];
  const void* w2 = d_in[8];
  const void* b2 = d_in[9];
  const void* outw = d_in[10];
  const void* outb = d_in[11];

  float* ws = (float*)d_ws;
  int* flagp = (int*)d_ws;
  const size_t O_RELAT = 16;
  const size_t O_AF = O_RELAT + 16384;
  const size_t O_BF = O_AF + 262144;
  const size_t O_AH = O_BF + 262144;
  const size_t O_BH = O_AH + 262144;
  const size_t O_ATTR = O_BH + 262144;
  const size_t O_DOT = O_ATTR + 65536;
  const size_t O_SP = O_DOT + 65536;
  const size_t O_W1B = O_SP + 1024;        // 65536 bf16
  const size_t O_RWB = O_W1B + 32768;      // 16384 bf16
  const size_t O_NSB = O_RWB + 8192;       // 4.19M bf16
  const size_t O_TUP = O_NSB + 2097152;    // 16.8M bf16

  float* relaT = ws + O_RELAT;
  float* Af = ws + O_AF;
  float* Bf = ws + O_BF;
  float* Ah = ws + O_AH;
  float* Bh = ws + O_BH;
  float* attr = ws + O_ATTR;
  float* dotv = ws + O_DOT;
  float* sp = ws + O_SP;
  __hip_bfloat16* w1b = (__hip_bfloat16*)(ws + O_W1B);
  __hip_bfloat16* rwb = (__hip_bfloat16*)(ws + O_RWB);
  __hip_bfloat16* nsb = (__hip_bfloat16*)(ws + O_NSB);
  __hip_bfloat16* tup = (__hip_bfloat16*)(ws + O_TUP);

  hipLaunchKernelGGL(k_detect, dim3(1), dim3(256), 0, stream,
                     (const unsigned int*)emb, flagp);
  hipLaunchKernelGGL(k_prep, dim3(2369), dim3(256), 0, stream,
                     rela, relaT, b1, w2, outw, b2, outb, sp,
                     w1, w1b, head, tail, emb, Af, Bf, flagp);
  hipLaunchKernelGGL(k_premm, dim3(528), dim3(256), 0, stream,
                     Af, Bf, rela, fcw, fcb, Ah, Bh, rwb, flagp);
  hipLaunchKernelGGL(k_scores, dim3(1024), dim3(256), 0, stream,
                     Af, Bf, relaT, d_out, nsb, flagp);
  hipLaunchKernelGGL(k_tuple2, dim3(1024), dim3(256), 0, stream,
                     nsb, rwb, Ah, Bh, tup);
  hipLaunchKernelGGL(k_att2, dim3(512), dim3(256), 0, stream,
                     tup, w1b, sp, attr, dotv);
  hipLaunchKernelGGL(k_fuse, dim3(16), dim3(256), 0, stream,
                     attr, dotv, sp, d_out, flagp);
}

// Round 9
// 259.312 us; speedup vs baseline: 1.1545x; 1.0125x over previous
//
#include <hip/hip_runtime.h>
#include <hip/hip_bf16.h>

#define NB 16
#define NW 64
#define NV 64
#define ND 256
#define NR 64
#define NN 4096
#define NEGV -10000000000.0f

typedef __attribute__((ext_vector_type(8))) short short8;
typedef __attribute__((ext_vector_type(4))) float f32x4;

__device__ inline float cvt(const void* p, int idx, int flag) {
  if (flag) return __bfloat162float(((const __hip_bfloat16*)p)[idx]);
  return ((const float*)p)[idx];
}
__device__ inline void stv(void* p, int idx, float v, int flag) {
  if (flag) ((__hip_bfloat16*)p)[idx] = __float2bfloat16(v);
  else ((float*)p)[idx] = v;
}
__device__ inline float bf2f(short s) {
  return __uint_as_float(((unsigned int)(unsigned short)s) << 16);
}
__device__ inline float tanh_fast(float x) {
  float ax = fabsf(x);
  float e = __expf(-2.f * ax);
  float r = (1.f - e) / (1.f + e);
  return copysignf(r, x);
}

// ---------- K0: detect input dtype (bf16 vs f32) ----------
__global__ void k_detect(const unsigned int* embw, int* flagp) {
  __shared__ float red[256];
  int t = threadIdx.x;
  float mx = 0.f;
  for (int i = t; i < 1024; i += 256) {
    unsigned int w = embw[i];
    unsigned int fb = (w & 0xffffu) << 16;
    float a = fabsf(__uint_as_float(fb));
    if (!(a < 1e9f)) a = 1e9f;
    mx = fmaxf(mx, a);
  }
  red[t] = mx;
  __syncthreads();
  for (int s = 128; s > 0; s >>= 1) {
    if (t < s) red[t] = fmaxf(red[t], red[t + s]);
    __syncthreads();
  }
  if (t == 0) flagp[0] = (red[0] < 1000.f) ? 1 : 0;
}

// ---------- K1 (merged prep): relaT | small params | w1 pack | gather ----------
__global__ void k_prep(const void* rela, float* relaT,
                       const void* b1, const void* w2, const void* outw,
                       const void* b2, const void* outb, float* sp,
                       const void* w1, __hip_bfloat16* w1b,
                       const int* head, const int* tail, const void* emb,
                       float* Af, float* Bf, const int* flagp) {
  int flag = flagp[0];
  int blk = blockIdx.x;
  int t = threadIdx.x;
  if (blk < 64) {
    relaT[t * NR + blk] = cvt(rela, blk * ND + t, flag);
  } else if (blk == 64) {
    sp[t] = cvt(b1, t, flag);
    sp[256 + t] = cvt(w2, t, flag);
    sp[512 + t] = cvt(outw, t, flag);
    if (t == 0) {
      sp[768] = cvt(b2, 0, flag);
      sp[769] = cvt(outb, 0, flag);
    }
  } else if (blk < 321) {
    int flat = (blk - 65) * 256 + t;  // 65536
    int i = flat & 7;
    int lane = (flat >> 3) & 63;
    int kst = (flat >> 9) & 7;
    int nt = flat >> 12;
    int k = kst * 32 + (lane >> 4) * 8 + i;
    int n = nt * 16 + (lane & 15);
    w1b[flat] = __float2bfloat16(cvt(w1, k * ND + n, flag));
  } else {
    int row = blk - 321;  // 0..2047
    if (row < NB * NW) {
      int ix = head[row];
      Af[row * ND + t] = cvt(emb, ix * ND + t, flag);
    } else {
      int rr = row - NB * NW;
      int ix = tail[rr];
      Bf[rr * ND + t] = cvt(emb, ix * ND + t, flag);
    }
  }
}

// ---------- K3: Ah = A@Wa + fc_b, Bh = B@Wb, RWb = pack(rela@Wc) ----------
__global__ void __launch_bounds__(256) k_premm(const float* __restrict__ Af,
                                               const float* __restrict__ Bf,
                                               const void* __restrict__ rela,
                                               const void* __restrict__ fcw,
                                               const void* __restrict__ fcb,
                                               float* __restrict__ Ah,
                                               float* __restrict__ Bh,
                                               __hip_bfloat16* __restrict__ rwb,
                                               const int* __restrict__ flagp) {
  int flag = flagp[0];
  int blk = blockIdx.x;
  int t = threadIdx.x;
  __shared__ float rl[4][ND];
  int base, wbase, addb = 0, isr = 0;
  const float* src = Af;
  if (blk < 256) { base = blk * 4; wbase = 0; addb = 1; }
  else if (blk < 512) { base = (blk - 256) * 4; src = Bf; wbase = ND; }
  else { base = (blk - 512) * 4; wbase = 2 * ND; isr = 1; }
#pragma unroll
  for (int i = 0; i < 4; ++i)
    rl[i][t] = isr ? cvt(rela, (base + i) * ND + t, flag)
                   : src[(base + i) * ND + t];
  __syncthreads();
  float acc0 = 0.f, acc1 = 0.f, acc2 = 0.f, acc3 = 0.f;
  const f32x4* r0p = (const f32x4*)rl[0];
  const f32x4* r1p = (const f32x4*)rl[1];
  const f32x4* r2p = (const f32x4*)rl[2];
  const f32x4* r3p = (const f32x4*)rl[3];
#pragma unroll 4
  for (int k4 = 0; k4 < 64; ++k4) {
    float w0 = cvt(fcw, (wbase + k4 * 4 + 0) * ND + t, flag);
    float w1v = cvt(fcw, (wbase + k4 * 4 + 1) * ND + t, flag);
    float w2v = cvt(fcw, (wbase + k4 * 4 + 2) * ND + t, flag);
    float w3v = cvt(fcw, (wbase + k4 * 4 + 3) * ND + t, flag);
    f32x4 r0 = r0p[k4], r1 = r1p[k4], r2 = r2p[k4], r3 = r3p[k4];
    acc0 += r0.x * w0 + r0.y * w1v + r0.z * w2v + r0.w * w3v;
    acc1 += r1.x * w0 + r1.y * w1v + r1.z * w2v + r1.w * w3v;
    acc2 += r2.x * w0 + r2.y * w1v + r2.z * w2v + r2.w * w3v;
    acc3 += r3.x * w0 + r3.y * w1v + r3.z * w2v + r3.w * w3v;
  }
  float bias = addb ? cvt(fcb, t, flag) : 0.f;
  float res[4] = {acc0 + bias, acc1 + bias, acc2 + bias, acc3 + bias};
  if (!isr) {
    float* dst = addb ? Ah : Bh;
#pragma unroll
    for (int i = 0; i < 4; ++i) dst[(base + i) * ND + t] = res[i];
  } else {
#pragma unroll
    for (int i = 0; i < 4; ++i) {
      int rr = base + i;
      int ks = rr >> 5, ii = rr & 7, lh = (rr >> 3) & 3;
      int nt = t >> 4, ll = t & 15;
      int flat = ((nt * 2 + ks) * 64 + lh * 16 + ll) * 8 + ii;
      rwb[flat] = __float2bfloat16(res[i]);
    }
  }
}

// ---------- K4: scores -> mask -> softmax -> norm_scores ----------
// R5's proven vector/LDS structure + (a) float4 staging (1 load + 1
// ds_write_b128 per thread/jg), (b) double-buffered Bl AND part with softmax
// pipelined one jg behind -> ONE barrier per jg, (c) register prefetch of the
// next jg's B row. Per-(b,i,j) FP op order bit-identical to R4/R5 (knife-edge
// s<=null mask must stay bit-stable f32).
__global__ void __launch_bounds__(256) k_scores(const float* __restrict__ Af,
                                                const float* __restrict__ Bf,
                                                const float* __restrict__ relaT,
                                                void* __restrict__ out,
                                                __hip_bfloat16* __restrict__ nsb,
                                                const int* __restrict__ flagp) {
  int flag = flagp[0];
  int bi = blockIdx.x;         // 1024 = b*64 + i
  int b = bi >> 6;
  int t = threadIdx.x;         // 256
  int r = t & 63;
  int q = t >> 6;              // wave index = d-quarter = staged row = softmax j4
  __shared__ float Al[ND];
  __shared__ float Bl[2][4 * ND];
  __shared__ float part[2][4 * 256];
  Al[t] = Af[bi * ND + t];
  // prefetch jg=0: wave q loads B row (jg*4+q) as float4 (64 lanes x 16B = 1KB)
  f32x4 pre = *(const f32x4*)(Bf + ((size_t)b * NV + q) * ND + r * 4);
  __syncthreads();
  float preR[64];
#pragma unroll
  for (int i2 = 0; i2 < 64; ++i2) {
    int d = q * 64 + i2;
    preR[i2] = Al[d] * relaT[d * NR + r];
  }

  for (int jg = 0; jg < 16; ++jg) {
    int buf = jg & 1;
    // stage prefetched row, then issue next prefetch (overlaps compute)
    *(f32x4*)(&Bl[buf][q * ND + r * 4]) = pre;
    if (jg < 15)
      pre = *(const f32x4*)(Bf + ((size_t)b * NV + (jg + 1) * 4 + q) * ND + r * 4);
    __syncthreads();   // Bl[buf] visible; part[1-buf] (prev jg) visible

    // softmax for PREVIOUS jg (pipelined; reads part[1-buf])
    if (jg > 0) {
      const float* pb = part[1 - buf];
      float s = pb[q * 256 + r] + pb[q * 256 + 64 + r]
              + pb[q * 256 + 128 + r] + pb[q * 256 + 192 + r];
      float nullv = __shfl(s, 63, 64);
      float m = (s <= nullv) ? NEGV : s;
      float mx = m;
#pragma unroll
      for (int o = 32; o > 0; o >>= 1) mx = fmaxf(mx, __shfl_xor(mx, o, 64));
      float e = __expf(m - mx);
      float sum = e;
#pragma unroll
      for (int o = 32; o > 0; o >>= 1) sum += __shfl_xor(sum, o, 64);
      float ns = e / sum;
      int j = (jg - 1) * 4 + q;
      int nidx = (bi * 64 + j) * 64 + r;
      stv(out, 16 + NB * NN + nidx, ns, flag);
      nsb[nidx] = __float2bfloat16(ns);
    }

    // compute this jg's partials (bit-identical FMA order to R5)
    const f32x4* Bl4 = (const f32x4*)Bl[buf];
#pragma unroll
    for (int jj = 0; jj < 4; ++jj) {
      float acc = 0.f;
      int ib = jj * 64 + q * 16;
#pragma unroll
      for (int i4 = 0; i4 < 16; ++i4) {
        f32x4 bv = Bl4[ib + i4];
        acc += preR[i4 * 4 + 0] * bv.x;
        acc += preR[i4 * 4 + 1] * bv.y;
        acc += preR[i4 * 4 + 2] * bv.z;
        acc += preR[i4 * 4 + 3] * bv.w;
      }
      part[buf][jj * 256 + t] = acc;
    }
  }
  __syncthreads();
  // final softmax (jg = 15, buf = 1)
  {
    const float* pb = part[1];
    float s = pb[q * 256 + r] + pb[q * 256 + 64 + r]
            + pb[q * 256 + 128 + r] + pb[q * 256 + 192 + r];
    float nullv = __shfl(s, 63, 64);
    float m = (s <= nullv) ? NEGV : s;
    float mx = m;
#pragma unroll
    for (int o = 32; o > 0; o >>= 1) mx = fmaxf(mx, __shfl_xor(mx, o, 64));
    float e = __expf(m - mx);
    float sum = e;
#pragma unroll
    for (int o = 32; o > 0; o >>= 1) sum += __shfl_xor(sum, o, 64);
    float ns = e / sum;
    int j = 15 * 4 + q;
    int nidx = (bi * 64 + j) * 64 + r;
    stv(out, 16 + NB * NN + nidx, ns, flag);
    nsb[nidx] = __float2bfloat16(ns);
  }
}

// ---------- K5 (MFMA): tuple = tanh(NS@RW + Ah + Bh) -> bf16 ----------
__global__ void __launch_bounds__(256) k_tuple2(const __hip_bfloat16* __restrict__ nsb,
                                                const __hip_bfloat16* __restrict__ rwb,
                                                const float* __restrict__ Ah,
                                                const float* __restrict__ Bh,
                                                __hip_bfloat16* __restrict__ tup) {
  int t = threadIdx.x;
  int wv = t >> 6, lane = t & 63;
  int bi = blockIdx.x;       // 1024
  int b = bi >> 6;
  const short* nsS = (const short*)nsb;
  const short* rwS = (const short*)rwb;
  int m = lane & 15;
  int kgrp = lane >> 4;
  f32x4 acc[16];
#pragma unroll
  for (int i = 0; i < 16; ++i) acc[i] = (f32x4){0.f, 0.f, 0.f, 0.f};
  int nrow = bi * 64 + wv * 16 + m;
#pragma unroll
  for (int ks = 0; ks < 2; ++ks) {
    short8 a = *(const short8*)(nsS + (size_t)nrow * 64 + ks * 32 + kgrp * 8);
#pragma unroll
    for (int nt = 0; nt < 16; ++nt) {
      short8 bfr = *(const short8*)(rwS + (((nt * 2 + ks) * 64 + lane) << 3));
      acc[nt] = __builtin_amdgcn_mfma_f32_16x16x32_bf16(a, bfr, acc[nt], 0, 0, 0);
    }
  }
  int rbase = bi * 64 + wv * 16 + (lane >> 4) * 4;
  int jbase = rbase & 63;
#pragma unroll
  for (int nt = 0; nt < 16; ++nt) {
    int col = nt * 16 + m;
    float ahv = Ah[bi * ND + col];
#pragma unroll
    for (int reg = 0; reg < 4; ++reg) {
      int ng = rbase + reg;
      float v = acc[nt][reg] + ahv + Bh[(size_t)(b * 64 + jbase + reg) * ND + col];
      tup[(size_t)ng * ND + col] = __float2bfloat16(tanh_fast(v));
    }
  }
}

// ---------- K6 (MFMA): att_raw = tanh(T@W1+b1)@w2+b2 ; dotv = T@out_w ----------
// 1024 blocks x 64 rows (4 blocks/CU — latency-bound kernel, occupancy lever).
__global__ void __launch_bounds__(256) k_att2(const __hip_bfloat16* __restrict__ tup,
                                              const __hip_bfloat16* __restrict__ w1b,
                                              const float* __restrict__ sp,
                                              float* __restrict__ att_raw,
                                              float* __restrict__ dotv) {
  int t = threadIdx.x;
  int wv = t >> 6, lane = t & 63;
  int r0 = blockIdx.x * 64 + wv * 16;
  const short* tupS = (const short*)tup;
  const short* w1S = (const short*)w1b;
  const float* owf = sp + 512;
  float b2v = sp[768];

  f32x4 acc[16];
#pragma unroll
  for (int i = 0; i < 16; ++i) acc[i] = (f32x4){0.f, 0.f, 0.f, 0.f};
  float dp = 0.f;
  int arow = r0 + (lane & 15);
  int kgrp = lane >> 4;

#pragma unroll
  for (int ks = 0; ks < 8; ++ks) {
    int k0 = ks * 32 + kgrp * 8;
    short8 a = *(const short8*)(tupS + (size_t)arow * ND + k0);
#pragma unroll
    for (int i = 0; i < 8; ++i)
      dp += bf2f(a[i]) * owf[k0 + i];
#pragma unroll
    for (int nt = 0; nt < 16; ++nt) {
      short8 bfr = *(const short8*)(w1S + (((nt * 8 + ks) * 64 + lane) << 3));
      acc[nt] = __builtin_amdgcn_mfma_f32_16x16x32_bf16(a, bfr, acc[nt], 0, 0, 0);
    }
  }

  dp += __shfl_xor(dp, 16, 64);
  dp += __shfl_xor(dp, 32, 64);
  if (lane < 16) dotv[r0 + lane] = dp;

  float p0[4] = {0.f, 0.f, 0.f, 0.f};
#pragma unroll
  for (int nt = 0; nt < 16; ++nt) {
    int col = nt * 16 + (lane & 15);
    float b1v = sp[col];
    float w2v = sp[256 + col];
#pragma unroll
    for (int reg = 0; reg < 4; ++reg)
      p0[reg] += tanh_fast(acc[nt][reg] + b1v) * w2v;
  }
#pragma unroll
  for (int o = 1; o < 16; o <<= 1) {
#pragma unroll
    for (int reg = 0; reg < 4; ++reg)
      p0[reg] += __shfl_xor(p0[reg], o, 64);
  }
  if ((lane & 15) == 0) {
    int rb = r0 + (lane >> 4) * 4;
#pragma unroll
    for (int reg = 0; reg < 4; ++reg)
      att_raw[rb + reg] = p0[reg] + b2v;
  }
}

// ---------- K7: att softmax over N -> att_norms out; logits ----------
__global__ void k_fuse(const float* att_raw, const float* dotv,
                       const float* sp, void* out, const int* flagp) {
  int flag = flagp[0];
  int b = blockIdx.x;
  int t = threadIdx.x;
  __shared__ float red[256];
  float vals[16];
  float mx = -3.4e38f;
#pragma unroll
  for (int c = 0; c < 16; ++c) {
    vals[c] = att_raw[b * NN + c * 256 + t];
    mx = fmaxf(mx, vals[c]);
  }
  red[t] = mx;
  __syncthreads();
  for (int s = 128; s > 0; s >>= 1) {
    if (t < s) red[t] = fmaxf(red[t], red[t + s]);
    __syncthreads();
  }
  float M = red[0];
  __syncthreads();
  float sm = 0.f;
#pragma unroll
  for (int c = 0; c < 16; ++c) {
    vals[c] = __expf(vals[c] - M);
    sm += vals[c];
  }
  red[t] = sm;
  __syncthreads();
  for (int s = 128; s > 0; s >>= 1) {
    if (t < s) red[t] += red[t + s];
    __syncthreads();
  }
  float Z = red[0];
  __syncthreads();
  float acc = 0.f;
#pragma unroll
  for (int c = 0; c < 16; ++c) {
    int n = c * 256 + t;
    float a = vals[c] / Z;
    stv(out, 16 + b * NN + n, a, flag);
    acc += a * dotv[b * NN + n];
  }
  red[t] = acc;
  __syncthreads();
  for (int s = 128; s > 0; s >>= 1) {
    if (t < s) red[t] += red[t + s];
    __syncthreads();
  }
  if (t == 0) stv(out, b, red[0] + sp[769], flag);   // + out_b
}

// ---------- host ----------
extern "C" void kernel_launch(void* const* d_in, const int* in_sizes, int n_in,
                              void* d_out, int out_size, void* d_ws, size_t ws_size,
                              hipStream_t stream) {
  const int* head = (const int*)d_in[0];
  const int* tail = (const int*)d_in[1];
  const void* emb = d_in[2];
  const void* rela = d_in[3];
  const void* fcw = d_in[4];
  const void* fcb = d_in[5];
  const void* w1 = d_in[6];
  const void* b1 = d_in[7];
  const void* w2 = d_in[8];
  const void* b2 = d_in[9];
  const void* outw = d_in[10];
  const void* outb = d_in[11];

  float* ws = (float*)d_ws;
  int* flagp = (int*)d_ws;
  const size_t O_RELAT = 16;
  const size_t O_AF = O_RELAT + 16384;
  const size_t O_BF = O_AF + 262144;
  const size_t O_AH = O_BF + 262144;
  const size_t O_BH = O_AH + 262144;
  const size_t O_ATTR = O_BH + 262144;
  const size_t O_DOT = O_ATTR + 65536;
  const size_t O_SP = O_DOT + 65536;
  const size_t O_W1B = O_SP + 1024;        // 65536 bf16
  const size_t O_RWB = O_W1B + 32768;      // 16384 bf16
  const size_t O_NSB = O_RWB + 8192;       // 4.19M bf16
  const size_t O_TUP = O_NSB + 2097152;    // 16.8M bf16

  float* relaT = ws + O_RELAT;
  float* Af = ws + O_AF;
  float* Bf = ws + O_BF;
  float* Ah = ws + O_AH;
  float* Bh = ws + O_BH;
  float* attr = ws + O_ATTR;
  float* dotv = ws + O_DOT;
  float* sp = ws + O_SP;
  __hip_bfloat16* w1b = (__hip_bfloat16*)(ws + O_W1B);
  __hip_bfloat16* rwb = (__hip_bfloat16*)(ws + O_RWB);
  __hip_bfloat16* nsb = (__hip_bfloat16*)(ws + O_NSB);
  __hip_bfloat16* tup = (__hip_bfloat16*)(ws + O_TUP);

  hipLaunchKernelGGL(k_detect, dim3(1), dim3(256), 0, stream,
                     (const unsigned int*)emb, flagp);
  hipLaunchKernelGGL(k_prep, dim3(2369), dim3(256), 0, stream,
                     rela, relaT, b1, w2, outw, b2, outb, sp,
                     w1, w1b, head, tail, emb, Af, Bf, flagp);
  hipLaunchKernelGGL(k_premm, dim3(528), dim3(256), 0, stream,
                     Af, Bf, rela, fcw, fcb, Ah, Bh, rwb, flagp);
  hipLaunchKernelGGL(k_scores, dim3(1024), dim3(256), 0, stream,
                     Af, Bf, relaT, d_out, nsb, flagp);
  hipLaunchKernelGGL(k_tuple2, dim3(1024), dim3(256), 0, stream,
                     nsb, rwb, Ah, Bh, tup);
  hipLaunchKernelGGL(k_att2, dim3(1024), dim3(256), 0, stream,
                     tup, w1b, sp, attr, dotv);
  hipLaunchKernelGGL(k_fuse, dim3(16), dim3(256), 0, stream,
                     attr, dotv, sp, d_out, flagp);
}

// Round 10
// 238.344 us; speedup vs baseline: 1.2561x; 1.0880x over previous
//
#include <hip/hip_runtime.h>
#include <hip/hip_bf16.h>

#define NB 16
#define NW 64
#define NV 64
#define ND 256
#define NR 64
#define NN 4096
#define NEGV -10000000000.0f

typedef __attribute__((ext_vector_type(8))) short short8;
typedef __attribute__((ext_vector_type(4))) float f32x4;

__device__ inline float cvt(const void* p, int idx, int flag) {
  if (flag) return __bfloat162float(((const __hip_bfloat16*)p)[idx]);
  return ((const float*)p)[idx];
}
__device__ inline void stv(void* p, int idx, float v, int flag) {
  if (flag) ((__hip_bfloat16*)p)[idx] = __float2bfloat16(v);
  else ((float*)p)[idx] = v;
}
__device__ inline float bf2f(short s) {
  return __uint_as_float(((unsigned int)(unsigned short)s) << 16);
}
__device__ inline float tanh_fast(float x) {
  float ax = fabsf(x);
  float e = __expf(-2.f * ax);
  float r = (1.f - e) / (1.f + e);
  return copysignf(r, x);
}

// ---------- K0: detect input dtype (bf16 vs f32) ----------
__global__ void k_detect(const unsigned int* embw, int* flagp) {
  __shared__ float red[256];
  int t = threadIdx.x;
  float mx = 0.f;
  for (int i = t; i < 1024; i += 256) {
    unsigned int w = embw[i];
    unsigned int fb = (w & 0xffffu) << 16;
    float a = fabsf(__uint_as_float(fb));
    if (!(a < 1e9f)) a = 1e9f;
    mx = fmaxf(mx, a);
  }
  red[t] = mx;
  __syncthreads();
  for (int s = 128; s > 0; s >>= 1) {
    if (t < s) red[t] = fmaxf(red[t], red[t + s]);
    __syncthreads();
  }
  if (t == 0) flagp[0] = (red[0] < 1000.f) ? 1 : 0;
}

// ---------- K1 (merged prep): relaT | small params | w1 pack | gather ----------
// w1b packing is KS-MAJOR: flat = ((ks*16 + nt)*64 + lane)*8 + i holds
// W1[k][n] with k = ks*32 + (lane>>4)*8 + i, n = nt*16 + (lane&15).
// -> each ks chunk (16 KB) is contiguous for LDS staging in k_att3.
__global__ void k_prep(const void* rela, float* relaT,
                       const void* b1, const void* w2, const void* outw,
                       const void* b2, const void* outb, float* sp,
                       const void* w1, __hip_bfloat16* w1b,
                       const int* head, const int* tail, const void* emb,
                       float* Af, float* Bf, const int* flagp) {
  int flag = flagp[0];
  int blk = blockIdx.x;
  int t = threadIdx.x;
  if (blk < 64) {
    relaT[t * NR + blk] = cvt(rela, blk * ND + t, flag);
  } else if (blk == 64) {
    sp[t] = cvt(b1, t, flag);
    sp[256 + t] = cvt(w2, t, flag);
    sp[512 + t] = cvt(outw, t, flag);
    if (t == 0) {
      sp[768] = cvt(b2, 0, flag);
      sp[769] = cvt(outb, 0, flag);
    }
  } else if (blk < 321) {
    int flat = (blk - 65) * 256 + t;  // 65536
    int i = flat & 7;
    int lane = (flat >> 3) & 63;
    int nt = (flat >> 9) & 15;
    int ks = flat >> 13;
    int k = ks * 32 + (lane >> 4) * 8 + i;
    int n = nt * 16 + (lane & 15);
    w1b[flat] = __float2bfloat16(cvt(w1, k * ND + n, flag));
  } else {
    int row = blk - 321;  // 0..2047
    if (row < NB * NW) {
      int ix = head[row];
      Af[row * ND + t] = cvt(emb, ix * ND + t, flag);
    } else {
      int rr = row - NB * NW;
      int ix = tail[rr];
      Bf[rr * ND + t] = cvt(emb, ix * ND + t, flag);
    }
  }
}

// ---------- K3: Ah = A@Wa + fc_b, Bh = B@Wb, RWb = pack(rela@Wc) ----------
__global__ void __launch_bounds__(256) k_premm(const float* __restrict__ Af,
                                               const float* __restrict__ Bf,
                                               const void* __restrict__ rela,
                                               const void* __restrict__ fcw,
                                               const void* __restrict__ fcb,
                                               float* __restrict__ Ah,
                                               float* __restrict__ Bh,
                                               __hip_bfloat16* __restrict__ rwb,
                                               const int* __restrict__ flagp) {
  int flag = flagp[0];
  int blk = blockIdx.x;
  int t = threadIdx.x;
  __shared__ float rl[4][ND];
  int base, wbase, addb = 0, isr = 0;
  const float* src = Af;
  if (blk < 256) { base = blk * 4; wbase = 0; addb = 1; }
  else if (blk < 512) { base = (blk - 256) * 4; src = Bf; wbase = ND; }
  else { base = (blk - 512) * 4; wbase = 2 * ND; isr = 1; }
#pragma unroll
  for (int i = 0; i < 4; ++i)
    rl[i][t] = isr ? cvt(rela, (base + i) * ND + t, flag)
                   : src[(base + i) * ND + t];
  __syncthreads();
  float acc0 = 0.f, acc1 = 0.f, acc2 = 0.f, acc3 = 0.f;
  const f32x4* r0p = (const f32x4*)rl[0];
  const f32x4* r1p = (const f32x4*)rl[1];
  const f32x4* r2p = (const f32x4*)rl[2];
  const f32x4* r3p = (const f32x4*)rl[3];
#pragma unroll 4
  for (int k4 = 0; k4 < 64; ++k4) {
    float w0 = cvt(fcw, (wbase + k4 * 4 + 0) * ND + t, flag);
    float w1v = cvt(fcw, (wbase + k4 * 4 + 1) * ND + t, flag);
    float w2v = cvt(fcw, (wbase + k4 * 4 + 2) * ND + t, flag);
    float w3v = cvt(fcw, (wbase + k4 * 4 + 3) * ND + t, flag);
    f32x4 r0 = r0p[k4], r1 = r1p[k4], r2 = r2p[k4], r3 = r3p[k4];
    acc0 += r0.x * w0 + r0.y * w1v + r0.z * w2v + r0.w * w3v;
    acc1 += r1.x * w0 + r1.y * w1v + r1.z * w2v + r1.w * w3v;
    acc2 += r2.x * w0 + r2.y * w1v + r2.z * w2v + r2.w * w3v;
    acc3 += r3.x * w0 + r3.y * w1v + r3.z * w2v + r3.w * w3v;
  }
  float bias = addb ? cvt(fcb, t, flag) : 0.f;
  float res[4] = {acc0 + bias, acc1 + bias, acc2 + bias, acc3 + bias};
  if (!isr) {
    float* dst = addb ? Ah : Bh;
#pragma unroll
    for (int i = 0; i < 4; ++i) dst[(base + i) * ND + t] = res[i];
  } else {
#pragma unroll
    for (int i = 0; i < 4; ++i) {
      int rr = base + i;
      int ks = rr >> 5, ii = rr & 7, lh = (rr >> 3) & 3;
      int nt = t >> 4, ll = t & 15;
      int flat = ((nt * 2 + ks) * 64 + lh * 16 + ll) * 8 + ii;
      rwb[flat] = __float2bfloat16(res[i]);
    }
  }
}

// ---------- K4: scores -> mask -> softmax -> norm_scores (R9 pipelined) ----------
__global__ void __launch_bounds__(256) k_scores(const float* __restrict__ Af,
                                                const float* __restrict__ Bf,
                                                const float* __restrict__ relaT,
                                                void* __restrict__ out,
                                                __hip_bfloat16* __restrict__ nsb,
                                                const int* __restrict__ flagp) {
  int flag = flagp[0];
  int bi = blockIdx.x;         // 1024 = b*64 + i
  int b = bi >> 6;
  int t = threadIdx.x;         // 256
  int r = t & 63;
  int q = t >> 6;
  __shared__ float Al[ND];
  __shared__ float Bl[2][4 * ND];
  __shared__ float part[2][4 * 256];
  Al[t] = Af[bi * ND + t];
  f32x4 pre = *(const f32x4*)(Bf + ((size_t)b * NV + q) * ND + r * 4);
  __syncthreads();
  float preR[64];
#pragma unroll
  for (int i2 = 0; i2 < 64; ++i2) {
    int d = q * 64 + i2;
    preR[i2] = Al[d] * relaT[d * NR + r];
  }

  for (int jg = 0; jg < 16; ++jg) {
    int buf = jg & 1;
    *(f32x4*)(&Bl[buf][q * ND + r * 4]) = pre;
    if (jg < 15)
      pre = *(const f32x4*)(Bf + ((size_t)b * NV + (jg + 1) * 4 + q) * ND + r * 4);
    __syncthreads();

    if (jg > 0) {
      const float* pb = part[1 - buf];
      float s = pb[q * 256 + r] + pb[q * 256 + 64 + r]
              + pb[q * 256 + 128 + r] + pb[q * 256 + 192 + r];
      float nullv = __shfl(s, 63, 64);
      float m = (s <= nullv) ? NEGV : s;
      float mx = m;
#pragma unroll
      for (int o = 32; o > 0; o >>= 1) mx = fmaxf(mx, __shfl_xor(mx, o, 64));
      float e = __expf(m - mx);
      float sum = e;
#pragma unroll
      for (int o = 32; o > 0; o >>= 1) sum += __shfl_xor(sum, o, 64);
      float ns = e / sum;
      int j = (jg - 1) * 4 + q;
      int nidx = (bi * 64 + j) * 64 + r;
      stv(out, 16 + NB * NN + nidx, ns, flag);
      nsb[nidx] = __float2bfloat16(ns);
    }

    const f32x4* Bl4 = (const f32x4*)Bl[buf];
#pragma unroll
    for (int jj = 0; jj < 4; ++jj) {
      float acc = 0.f;
      int ib = jj * 64 + q * 16;
#pragma unroll
      for (int i4 = 0; i4 < 16; ++i4) {
        f32x4 bv = Bl4[ib + i4];
        acc += preR[i4 * 4 + 0] * bv.x;
        acc += preR[i4 * 4 + 1] * bv.y;
        acc += preR[i4 * 4 + 2] * bv.z;
        acc += preR[i4 * 4 + 3] * bv.w;
      }
      part[buf][jj * 256 + t] = acc;
    }
  }
  __syncthreads();
  {
    const float* pb = part[1];
    float s = pb[q * 256 + r] + pb[q * 256 + 64 + r]
            + pb[q * 256 + 128 + r] + pb[q * 256 + 192 + r];
    float nullv = __shfl(s, 63, 64);
    float m = (s <= nullv) ? NEGV : s;
    float mx = m;
#pragma unroll
    for (int o = 32; o > 0; o >>= 1) mx = fmaxf(mx, __shfl_xor(mx, o, 64));
    float e = __expf(m - mx);
    float sum = e;
#pragma unroll
    for (int o = 32; o > 0; o >>= 1) sum += __shfl_xor(sum, o, 64);
    float ns = e / sum;
    int j = 15 * 4 + q;
    int nidx = (bi * 64 + j) * 64 + r;
    stv(out, 16 + NB * NN + nidx, ns, flag);
    nsb[nidx] = __float2bfloat16(ns);
  }
}

// ---------- K5 (MFMA): tuple = tanh(NS@RW + Ah + Bh) -> bf16 ----------
// rwb (32 KB) staged in LDS ONCE per block -> B-fragments via ds_read, no
// serialized L2 latency chains.
__global__ void __launch_bounds__(256) k_tuple2(const __hip_bfloat16* __restrict__ nsb,
                                                const __hip_bfloat16* __restrict__ rwb,
                                                const float* __restrict__ Ah,
                                                const float* __restrict__ Bh,
                                                __hip_bfloat16* __restrict__ tup) {
  __shared__ __align__(16) short rwl[16384];   // 32 KB
  int t = threadIdx.x;
  int wv = t >> 6, lane = t & 63;
  int bi = blockIdx.x;       // 1024
  int b = bi >> 6;
  const short* nsS = (const short*)nsb;
  const short8* rwsrc = (const short8*)rwb;
  short8* rwdst = (short8*)rwl;
#pragma unroll
  for (int i = 0; i < 8; ++i) rwdst[t + 256 * i] = rwsrc[t + 256 * i];
  int m = lane & 15;
  int kgrp = lane >> 4;
  int nrow = bi * 64 + wv * 16 + m;
  short8 a0 = *(const short8*)(nsS + (size_t)nrow * 64 + kgrp * 8);
  short8 a1 = *(const short8*)(nsS + (size_t)nrow * 64 + 32 + kgrp * 8);
  __syncthreads();
  f32x4 acc[16];
#pragma unroll
  for (int i = 0; i < 16; ++i) acc[i] = (f32x4){0.f, 0.f, 0.f, 0.f};
#pragma unroll
  for (int nt = 0; nt < 16; ++nt) {
    short8 b0 = *(const short8*)(rwl + (((nt * 2 + 0) * 64 + lane) << 3));
    short8 b1f = *(const short8*)(rwl + (((nt * 2 + 1) * 64 + lane) << 3));
    acc[nt] = __builtin_amdgcn_mfma_f32_16x16x32_bf16(a0, b0, acc[nt], 0, 0, 0);
    acc[nt] = __builtin_amdgcn_mfma_f32_16x16x32_bf16(a1, b1f, acc[nt], 0, 0, 0);
  }
  int rbase = bi * 64 + wv * 16 + kgrp * 4;
  int jbase = rbase & 63;
#pragma unroll
  for (int nt = 0; nt < 16; ++nt) {
    int col = nt * 16 + m;
    float ahv = Ah[bi * ND + col];
#pragma unroll
    for (int reg = 0; reg < 4; ++reg) {
      int ng = rbase + reg;
      float v = acc[nt][reg] + ahv + Bh[(size_t)(b * 64 + jbase + reg) * ND + col];
      tup[(size_t)ng * ND + col] = __float2bfloat16(tanh_fast(v));
    }
  }
}

// ---------- K6 (MFMA): att_raw = tanh(T@W1+b1)@w2+b2 ; dotv = T@out_w ----------
// 512 blocks x 128 rows (2 M-tiles/wave = 2x fragment reuse). W1 fragments
// staged ks-chunk-wise into LDS, double-buffered: one barrier per ks, global
// loads for ks+1 overlap MFMA on ks. A-fragments register-prefetched.
__global__ void __launch_bounds__(256) k_att3(const __hip_bfloat16* __restrict__ tup,
                                              const __hip_bfloat16* __restrict__ w1b,
                                              const float* __restrict__ sp,
                                              float* __restrict__ att_raw,
                                              float* __restrict__ dotv) {
  __shared__ __align__(16) short bl[2][8192];   // 2 x 16 KB
  int t = threadIdx.x;
  int wv = t >> 6, lane = t & 63;
  int r0 = blockIdx.x * 128 + wv * 32;
  const short* tupS = (const short*)tup;
  const short8* w1v = (const short8*)w1b;       // 8192 short8 total, 1024/chunk
  const float* owf = sp + 512;
  float b2v = sp[768];
  int m = lane & 15;
  int kgrp = lane >> 4;
  int arow0 = r0 + m;
  int arow1 = arow0 + 16;

  // stage chunk 0
  {
    short8* dst = (short8*)bl[0];
#pragma unroll
    for (int i = 0; i < 4; ++i) dst[t + 256 * i] = w1v[t + 256 * i];
  }
  // prefetch A fragments for ks=0
  short8 a0 = *(const short8*)(tupS + (size_t)arow0 * ND + kgrp * 8);
  short8 a1 = *(const short8*)(tupS + (size_t)arow1 * ND + kgrp * 8);

  f32x4 acc0[16], acc1[16];
#pragma unroll
  for (int i = 0; i < 16; ++i) {
    acc0[i] = (f32x4){0.f, 0.f, 0.f, 0.f};
    acc1[i] = (f32x4){0.f, 0.f, 0.f, 0.f};
  }
  float dp0 = 0.f, dp1 = 0.f;

  for (int ks = 0; ks < 8; ++ks) {
    int buf = ks & 1;
    __syncthreads();   // chunk ks visible; prev reads of (1-buf) done
    if (ks < 7) {      // stage chunk ks+1 into other buffer (overlaps MFMA)
      const short8* src = w1v + (ks + 1) * 1024;
      short8* dst = (short8*)bl[1 - buf];
#pragma unroll
      for (int i = 0; i < 4; ++i) dst[t + 256 * i] = src[t + 256 * i];
    }
    short8 ca0 = a0, ca1 = a1;
    if (ks < 7) {      // prefetch next A fragments
      int k0n = (ks + 1) * 32 + kgrp * 8;
      a0 = *(const short8*)(tupS + (size_t)arow0 * ND + k0n);
      a1 = *(const short8*)(tupS + (size_t)arow1 * ND + k0n);
    }
    int k0 = ks * 32 + kgrp * 8;
#pragma unroll
    for (int i = 0; i < 8; ++i) {
      float w = owf[k0 + i];
      dp0 += bf2f(ca0[i]) * w;
      dp1 += bf2f(ca1[i]) * w;
    }
#pragma unroll
    for (int nt = 0; nt < 16; ++nt) {
      short8 bfr = *(const short8*)(bl[buf] + ((nt * 64 + lane) << 3));
      acc0[nt] = __builtin_amdgcn_mfma_f32_16x16x32_bf16(ca0, bfr, acc0[nt], 0, 0, 0);
      acc1[nt] = __builtin_amdgcn_mfma_f32_16x16x32_bf16(ca1, bfr, acc1[nt], 0, 0, 0);
    }
  }

  dp0 += __shfl_xor(dp0, 16, 64); dp0 += __shfl_xor(dp0, 32, 64);
  dp1 += __shfl_xor(dp1, 16, 64); dp1 += __shfl_xor(dp1, 32, 64);
  if (lane < 16) {
    dotv[r0 + lane] = dp0;
    dotv[r0 + 16 + lane] = dp1;
  }

  float p0[4] = {0.f, 0.f, 0.f, 0.f};
  float p1[4] = {0.f, 0.f, 0.f, 0.f};
#pragma unroll
  for (int nt = 0; nt < 16; ++nt) {
    int col = nt * 16 + m;
    float b1v = sp[col];
    float w2v = sp[256 + col];
#pragma unroll
    for (int reg = 0; reg < 4; ++reg) {
      p0[reg] += tanh_fast(acc0[nt][reg] + b1v) * w2v;
      p1[reg] += tanh_fast(acc1[nt][reg] + b1v) * w2v;
    }
  }
#pragma unroll
  for (int o = 1; o < 16; o <<= 1) {
#pragma unroll
    for (int reg = 0; reg < 4; ++reg) {
      p0[reg] += __shfl_xor(p0[reg], o, 64);
      p1[reg] += __shfl_xor(p1[reg], o, 64);
    }
  }
  if (m == 0) {
    int rb = r0 + kgrp * 4;
#pragma unroll
    for (int reg = 0; reg < 4; ++reg) {
      att_raw[rb + reg] = p0[reg] + b2v;
      att_raw[rb + 16 + reg] = p1[reg] + b2v;
    }
  }
}

// ---------- K7: att softmax over N -> att_norms out; logits ----------
__global__ void k_fuse(const float* att_raw, const float* dotv,
                       const float* sp, void* out, const int* flagp) {
  int flag = flagp[0];
  int b = blockIdx.x;
  int t = threadIdx.x;
  __shared__ float red[256];
  float vals[16];
  float mx = -3.4e38f;
#pragma unroll
  for (int c = 0; c < 16; ++c) {
    vals[c] = att_raw[b * NN + c * 256 + t];
    mx = fmaxf(mx, vals[c]);
  }
  red[t] = mx;
  __syncthreads();
  for (int s = 128; s > 0; s >>= 1) {
    if (t < s) red[t] = fmaxf(red[t], red[t + s]);
    __syncthreads();
  }
  float M = red[0];
  __syncthreads();
  float sm = 0.f;
#pragma unroll
  for (int c = 0; c < 16; ++c) {
    vals[c] = __expf(vals[c] - M);
    sm += vals[c];
  }
  red[t] = sm;
  __syncthreads();
  for (int s = 128; s > 0; s >>= 1) {
    if (t < s) red[t] += red[t + s];
    __syncthreads();
  }
  float Z = red[0];
  __syncthreads();
  float acc = 0.f;
#pragma unroll
  for (int c = 0; c < 16; ++c) {
    int n = c * 256 + t;
    float a = vals[c] / Z;
    stv(out, 16 + b * NN + n, a, flag);
    acc += a * dotv[b * NN + n];
  }
  red[t] = acc;
  __syncthreads();
  for (int s = 128; s > 0; s >>= 1) {
    if (t < s) red[t] += red[t + s];
    __syncthreads();
  }
  if (t == 0) stv(out, b, red[0] + sp[769], flag);   // + out_b
}

// ---------- host ----------
extern "C" void kernel_launch(void* const* d_in, const int* in_sizes, int n_in,
                              void* d_out, int out_size, void* d_ws, size_t ws_size,
                              hipStream_t stream) {
  const int* head = (const int*)d_in[0];
  const int* tail = (const int*)d_in[1];
  const void* emb = d_in[2];
  const void* rela = d_in[3];
  const void* fcw = d_in[4];
  const void* fcb = d_in[5];
  const void* w1 = d_in[6];
  const void* b1 = d_in[7];
  const void* w2 = d_in[8];
  const void* b2 = d_in[9];
  const void* outw = d_in[10];
  const void* outb = d_in[11];

  float* ws = (float*)d_ws;
  int* flagp = (int*)d_ws;
  const size_t O_RELAT = 16;
  const size_t O_AF = O_RELAT + 16384;
  const size_t O_BF = O_AF + 262144;
  const size_t O_AH = O_BF + 262144;
  const size_t O_BH = O_AH + 262144;
  const size_t O_ATTR = O_BH + 262144;
  const size_t O_DOT = O_ATTR + 65536;
  const size_t O_SP = O_DOT + 65536;
  const size_t O_W1B = O_SP + 1024;        // 65536 bf16
  const size_t O_RWB = O_W1B + 32768;      // 16384 bf16
  const size_t O_NSB = O_RWB + 8192;       // 4.19M bf16
  const size_t O_TUP = O_NSB + 2097152;    // 16.8M bf16

  float* relaT = ws + O_RELAT;
  float* Af = ws + O_AF;
  float* Bf = ws + O_BF;
  float* Ah = ws + O_AH;
  float* Bh = ws + O_BH;
  float* attr = ws + O_ATTR;
  float* dotv = ws + O_DOT;
  float* sp = ws + O_SP;
  __hip_bfloat16* w1b = (__hip_bfloat16*)(ws + O_W1B);
  __hip_bfloat16* rwb = (__hip_bfloat16*)(ws + O_RWB);
  __hip_bfloat16* nsb = (__hip_bfloat16*)(ws + O_NSB);
  __hip_bfloat16* tup = (__hip_bfloat16*)(ws + O_TUP);

  hipLaunchKernelGGL(k_detect, dim3(1), dim3(256), 0, stream,
                     (const unsigned int*)emb, flagp);
  hipLaunchKernelGGL(k_prep, dim3(2369), dim3(256), 0, stream,
                     rela, relaT, b1, w2, outw, b2, outb, sp,
                     w1, w1b, head, tail, emb, Af, Bf, flagp);
  hipLaunchKernelGGL(k_premm, dim3(528), dim3(256), 0, stream,
                     Af, Bf, rela, fcw, fcb, Ah, Bh, rwb, flagp);
  hipLaunchKernelGGL(k_scores, dim3(1024), dim3(256), 0, stream,
                     Af, Bf, relaT, d_out, nsb, flagp);
  hipLaunchKernelGGL(k_tuple2, dim3(1024), dim3(256), 0, stream,
                     nsb, rwb, Ah, Bh, tup);
  hipLaunchKernelGGL(k_att3, dim3(512), dim3(256), 0, stream,
                     tup, w1b, sp, attr, dotv);
  hipLaunchKernelGGL(k_fuse, dim3(16), dim3(256), 0, stream,
                     attr, dotv, sp, d_out, flagp);
}